// Round 2
// baseline (64012.103 us; speedup 1.0000x reference)
//
#include <hip/hip_runtime.h>

#define TT 256
#define BB 32
#define HH 1024
#define GG 4096

// ---------- transpose x[B,T,H] -> seq[T,B,H] ----------
__global__ __launch_bounds__(256) void k_transpose(const float* __restrict__ x, float* __restrict__ seq) {
    int idx = blockIdx.x * 256 + threadIdx.x;  // over T*B*H/4 float4s
    int k4 = idx & 255;                        // H/4 = 256
    int tb = idx >> 8;                         // t*B + b
    int t = tb >> 5, b = tb & 31;
    float4 v = ((const float4*)x)[((size_t)b * TT + t) * 256 + k4];
    ((float4*)seq)[(size_t)tb * 256 + k4] = v;
}

__global__ __launch_bounds__(256) void k_init_hc(const float* __restrict__ h0, const float* __restrict__ c0,
                                                 float* __restrict__ h, float* __restrict__ c) {
    int i = blockIdx.x * 256 + threadIdx.x;  // 8192 float4s
    ((float4*)h)[i] = ((const float4*)h0)[i];
    ((float4*)c)[i] = ((const float4*)c0)[i];
}

__global__ __launch_bounds__(256) void k_copy_hc(const float* __restrict__ h, const float* __restrict__ c,
                                                 float* __restrict__ oh, float* __restrict__ oc) {
    int i = blockIdx.x * 256 + threadIdx.x;
    ((float4*)oh)[i] = ((const float4*)h)[i];
    ((float4*)oc)[i] = ((const float4*)c)[i];
}

// ---------- fp32 GEMM: C[M,N] = A[M,1024] @ W[1024,N] + bias ----------
// MODE 0: C row-major [M,N].  MODE 1: row m = t*32+b is written to C[b][t][0:N] (head output).
template <int MODE>
__global__ __launch_bounds__(256) void k_gemm(const float* __restrict__ A, const float* __restrict__ W,
                                              const float* __restrict__ bias, float* __restrict__ C, int N) {
    __shared__ float As[16][132];
    __shared__ float Bs[16][132];
    const int K = 1024;
    int tid = threadIdx.x;
    int m0 = blockIdx.x * 128, n0 = blockIdx.y * 128;
    int tx = tid & 15, ty = tid >> 4;
    int a_row = tid >> 2, a_kq = tid & 3;
    int b_cq = tid & 31, b_k = tid >> 5;
    float acc[8][8];
#pragma unroll
    for (int i = 0; i < 8; ++i)
#pragma unroll
        for (int jj = 0; jj < 8; ++jj) acc[i][jj] = 0.f;

    for (int kc = 0; kc < K; kc += 16) {
#pragma unroll
        for (int it = 0; it < 2; ++it) {
            int row = a_row + it * 64;
            float4 v = *(const float4*)&A[(size_t)(m0 + row) * K + kc + a_kq * 4];
            As[a_kq * 4 + 0][row] = v.x;
            As[a_kq * 4 + 1][row] = v.y;
            As[a_kq * 4 + 2][row] = v.z;
            As[a_kq * 4 + 3][row] = v.w;
        }
#pragma unroll
        for (int it = 0; it < 2; ++it) {
            int kk = b_k + it * 8;
            float4 v = *(const float4*)&W[(size_t)(kc + kk) * N + n0 + b_cq * 4];
            *(float4*)&Bs[kk][b_cq * 4] = v;
        }
        __syncthreads();
#pragma unroll
        for (int kk = 0; kk < 16; ++kk) {
            float4 a0 = *(const float4*)&As[kk][ty * 8];
            float4 a1 = *(const float4*)&As[kk][ty * 8 + 4];
            float4 b0 = *(const float4*)&Bs[kk][tx * 8];
            float4 b1 = *(const float4*)&Bs[kk][tx * 8 + 4];
            float am[8] = {a0.x, a0.y, a0.z, a0.w, a1.x, a1.y, a1.z, a1.w};
            float bv[8] = {b0.x, b0.y, b0.z, b0.w, b1.x, b1.y, b1.z, b1.w};
#pragma unroll
            for (int i = 0; i < 8; ++i)
#pragma unroll
                for (int jj = 0; jj < 8; ++jj) acc[i][jj] += am[i] * bv[jj];
        }
        __syncthreads();
    }
#pragma unroll
    for (int i = 0; i < 8; ++i) {
        int m = m0 + ty * 8 + i;
#pragma unroll
        for (int jj = 0; jj < 8; jj += 4) {
            int n = n0 + tx * 8 + jj;
            float4 v;
            v.x = acc[i][jj + 0] + bias[n + 0];
            v.y = acc[i][jj + 1] + bias[n + 1];
            v.z = acc[i][jj + 2] + bias[n + 2];
            v.w = acc[i][jj + 3] + bias[n + 3];
            if (MODE == 0) {
                *(float4*)&C[(size_t)m * N + n] = v;
            } else {
                int t = m >> 5, b = m & 31;
                *(float4*)&C[((size_t)b * TT + t) * HH + n] = v;
            }
        }
    }
}

// ---------- one LSTM timestep (non-cooperative; kernel boundary = barrier) ----------
// 256 blocks x 256 threads. Block owns h-cols hc0..hc0+3 (16 gate cols).
// Thread (ks=tid>>4, j=tid&15): 64-k slice of the dot product for gate-col j.
// Wave butterfly over lane bits 4/5 reduces the 4 k-slices in a wave; LDS reduces the 4 waves.
__global__ __launch_bounds__(256) void k_step(const float* __restrict__ Wr, const float* __restrict__ xw_t,
                                              float* __restrict__ seq_t, const float* __restrict__ h_in,
                                              float* __restrict__ h_out, float* __restrict__ c) {
    __shared__ float zred[4][32][17];
    int tid = threadIdx.x;
    int j = tid & 15, ks = tid >> 4;
    int hc0 = blockIdx.x * 4;
    int col = (j >> 2) * HH + hc0 + (j & 3);   // gate g = j>>2, h-col d = j&3

    // load this thread's Wr column slice (64 k) into registers
    float4 w[16];
#pragma unroll
    for (int q = 0; q < 16; ++q) {
        size_t kb = (size_t)(ks * 64 + q * 4) * GG + col;
        w[q].x = Wr[kb];
        w[q].y = Wr[kb + GG];
        w[q].z = Wr[kb + 2 * (size_t)GG];
        w[q].w = Wr[kb + 3 * (size_t)GG];
    }

    // partial z = h @ Wr over the 64-k slice, all 32 batches
    const float4* hp = (const float4*)h_in;
    int kq0 = ks * 16;
    float acc[32];
#pragma unroll
    for (int b = 0; b < 32; ++b) acc[b] = 0.f;
#pragma unroll
    for (int q = 0; q < 16; ++q) {
        float4 wq = w[q];
#pragma unroll
        for (int b = 0; b < 32; ++b) {
            float4 hv = hp[b * 256 + kq0 + q];
            acc[b] += wq.x * hv.x + wq.y * hv.y + wq.z * hv.z + wq.w * hv.w;
        }
    }
    // reduce 4 k-slices within the wave (lane = (ks&3)*16 + j)
#pragma unroll
    for (int b = 0; b < 32; ++b) {
        acc[b] += __shfl_xor(acc[b], 16);
        acc[b] += __shfl_xor(acc[b], 32);
    }
    int wv = tid >> 6;
    if ((ks & 3) == 0) {
#pragma unroll
        for (int b = 0; b < 32; ++b) zred[wv][b][j] = acc[b];
    }
    __syncthreads();

    // reduce across waves + gates + state update
    if (tid < 128) {
        int rb = tid >> 2, rd = tid & 3;
        float zz[4];
#pragma unroll
        for (int g = 0; g < 4; ++g) {
            float s = xw_t[rb * GG + g * HH + hc0 + rd];
#pragma unroll
            for (int u = 0; u < 4; ++u) s += zred[u][rb][g * 4 + rd];
            zz[g] = s;
        }
        float si = 1.f / (1.f + expf(-zz[0]));
        float sf = 1.f / (1.f + expf(-zz[1]));
        float gg = fmaxf(zz[2], 0.f);
        float so = 1.f / (1.f + expf(-zz[3]));
        float cv = c[rb * HH + hc0 + rd];
        cv = sf * cv + si * gg;
        c[rb * HH + hc0 + rd] = cv;
        float hn = so * fmaxf(cv, 0.f);
        h_out[rb * HH + hc0 + rd] = hn;
        seq_t[rb * HH + hc0 + rd] = hn;
    }
}

extern "C" void kernel_launch(void* const* d_in, const int* in_sizes, int n_in,
                              void* d_out, int out_size, void* d_ws, size_t ws_size,
                              hipStream_t stream) {
    const float* x  = (const float*)d_in[0];
    const float* h0 = (const float*)d_in[1];
    const float* c0 = (const float*)d_in[2];
    const float* Wk = (const float*)d_in[3];
    const float* Wr = (const float*)d_in[4];
    const float* bs = (const float*)d_in[5];
    const float* Wd = (const float*)d_in[6];
    const float* bd = (const float*)d_in[7];
    float* out = (float*)d_out;
    float* ws  = (float*)d_ws;

    float* xw  = ws;                         // [T][B][4H]  = 33554432 f32 (128 MB)
    float* seq = ws + 33554432;              // [T][B][H]   =  8388608 f32 (32 MB)
    float* h0b = seq + 8388608;              // [B][H]
    float* h1b = h0b + 32768;                // [B][H]
    float* c   = h1b + 32768;                // [B][H]

    k_transpose<<<8192, 256, 0, stream>>>(x, seq);
    k_init_hc<<<32, 256, 0, stream>>>(h0, c0, h0b, c);

    for (int l = 0; l < 4; ++l) {
        k_gemm<0><<<dim3(64, 32), 256, 0, stream>>>(seq, Wk + (size_t)l * 1024 * 4096,
                                                    bs + l * 4096, xw, 4096);
        const float* Wrl = Wr + (size_t)l * 1024 * 4096;
        for (int t = 0; t < TT; ++t) {
            const float* hin = (t & 1) ? h1b : h0b;
            float* hout      = (t & 1) ? h0b : h1b;
            k_step<<<256, 256, 0, stream>>>(Wrl, xw + (size_t)t * (BB * GG),
                                            seq + (size_t)t * (BB * HH), hin, hout, c);
        }
    }

    k_gemm<1><<<dim3(64, 8), 256, 0, stream>>>(seq, Wd, bd, out, 1024);
    k_copy_hc<<<32, 256, 0, stream>>>(h0b, c, out + 8388608, out + 8388608 + 32768);
}

// Round 4
// 41418.567 us; speedup vs baseline: 1.5455x; 1.5455x over previous
//
#include <hip/hip_runtime.h>

#define TT 256
#define BB 32
#define HH 1024
#define GG 4096

// ---------- transpose x[B,T,H] -> seq[T,B,H] ----------
__global__ __launch_bounds__(256) void k_transpose(const float* __restrict__ x, float* __restrict__ seq) {
    int idx = blockIdx.x * 256 + threadIdx.x;  // over T*B*H/4 float4s
    int k4 = idx & 255;                        // H/4 = 256
    int tb = idx >> 8;                         // t*B + b
    int t = tb >> 5, b = tb & 31;
    float4 v = ((const float4*)x)[((size_t)b * TT + t) * 256 + k4];
    ((float4*)seq)[(size_t)tb * 256 + k4] = v;
}

__global__ __launch_bounds__(256) void k_init_hc(const float* __restrict__ h0, const float* __restrict__ c0,
                                                 float* __restrict__ h, float* __restrict__ c) {
    int i = blockIdx.x * 256 + threadIdx.x;  // 8192 float4s
    ((float4*)h)[i] = ((const float4*)h0)[i];
    ((float4*)c)[i] = ((const float4*)c0)[i];
}

__global__ __launch_bounds__(256) void k_copy_hc(const float* __restrict__ h, const float* __restrict__ c,
                                                 float* __restrict__ oh, float* __restrict__ oc) {
    int i = blockIdx.x * 256 + threadIdx.x;
    ((float4*)oh)[i] = ((const float4*)h)[i];
    ((float4*)oc)[i] = ((const float4*)c)[i];
}

// ---------- Wr[1024,4096] -> WrT[4096,1024] (64x64 LDS tiles) ----------
__global__ __launch_bounds__(256) void k_wrt(const float* __restrict__ Wr, float* __restrict__ WrT) {
    __shared__ float tile[64][65];
    int c0 = blockIdx.x * 64;   // col tile
    int k0 = blockIdx.y * 64;   // k tile
    int tid = threadIdx.x;
    int tr = tid >> 4, tc4 = tid & 15;
#pragma unroll
    for (int p = 0; p < 4; ++p) {
        int r = p * 16 + tr;
        float4 v = *(const float4*)&Wr[(size_t)(k0 + r) * GG + c0 + tc4 * 4];
        tile[r][tc4 * 4 + 0] = v.x;
        tile[r][tc4 * 4 + 1] = v.y;
        tile[r][tc4 * 4 + 2] = v.z;
        tile[r][tc4 * 4 + 3] = v.w;
    }
    __syncthreads();
#pragma unroll
    for (int p = 0; p < 4; ++p) {
        int cc = p * 16 + tr;
        float4 v;
        v.x = tile[tc4 * 4 + 0][cc];
        v.y = tile[tc4 * 4 + 1][cc];
        v.z = tile[tc4 * 4 + 2][cc];
        v.w = tile[tc4 * 4 + 3][cc];
        *(float4*)&WrT[(size_t)(c0 + cc) * 1024 + k0 + tc4 * 4] = v;
    }
}

// ---------- fp32 GEMM: C[M,N] = A[M,1024] @ W[1024,N] + bias ----------
template <int MODE>
__global__ __launch_bounds__(256) void k_gemm(const float* __restrict__ A, const float* __restrict__ W,
                                              const float* __restrict__ bias, float* __restrict__ C, int N) {
    __shared__ float As[16][132];
    __shared__ float Bs[16][132];
    const int K = 1024;
    int tid = threadIdx.x;
    int m0 = blockIdx.x * 128, n0 = blockIdx.y * 128;
    int tx = tid & 15, ty = tid >> 4;
    int a_row = tid >> 2, a_kq = tid & 3;
    int b_cq = tid & 31, b_k = tid >> 5;
    float acc[8][8];
#pragma unroll
    for (int i = 0; i < 8; ++i)
#pragma unroll
        for (int jj = 0; jj < 8; ++jj) acc[i][jj] = 0.f;

    for (int kc = 0; kc < K; kc += 16) {
#pragma unroll
        for (int it = 0; it < 2; ++it) {
            int row = a_row + it * 64;
            float4 v = *(const float4*)&A[(size_t)(m0 + row) * K + kc + a_kq * 4];
            As[a_kq * 4 + 0][row] = v.x;
            As[a_kq * 4 + 1][row] = v.y;
            As[a_kq * 4 + 2][row] = v.z;
            As[a_kq * 4 + 3][row] = v.w;
        }
#pragma unroll
        for (int it = 0; it < 2; ++it) {
            int kk = b_k + it * 8;
            float4 v = *(const float4*)&W[(size_t)(kc + kk) * N + n0 + b_cq * 4];
            *(float4*)&Bs[kk][b_cq * 4] = v;
        }
        __syncthreads();
#pragma unroll
        for (int kk = 0; kk < 16; ++kk) {
            float4 a0 = *(const float4*)&As[kk][ty * 8];
            float4 a1 = *(const float4*)&As[kk][ty * 8 + 4];
            float4 b0 = *(const float4*)&Bs[kk][tx * 8];
            float4 b1 = *(const float4*)&Bs[kk][tx * 8 + 4];
            float am[8] = {a0.x, a0.y, a0.z, a0.w, a1.x, a1.y, a1.z, a1.w};
            float bv[8] = {b0.x, b0.y, b0.z, b0.w, b1.x, b1.y, b1.z, b1.w};
#pragma unroll
            for (int i = 0; i < 8; ++i)
#pragma unroll
                for (int jj = 0; jj < 8; ++jj) acc[i][jj] += am[i] * bv[jj];
        }
        __syncthreads();
    }
#pragma unroll
    for (int i = 0; i < 8; ++i) {
        int m = m0 + ty * 8 + i;
#pragma unroll
        for (int jj = 0; jj < 8; jj += 4) {
            int n = n0 + tx * 8 + jj;
            float4 v;
            v.x = acc[i][jj + 0] + bias[n + 0];
            v.y = acc[i][jj + 1] + bias[n + 1];
            v.z = acc[i][jj + 2] + bias[n + 2];
            v.w = acc[i][jj + 3] + bias[n + 3];
            if (MODE == 0) {
                *(float4*)&C[(size_t)m * N + n] = v;
            } else {
                int t = m >> 5, b = m & 31;
                *(float4*)&C[((size_t)b * TT + t) * HH + n] = v;
            }
        }
    }
}

// ---------- one LSTM timestep, WrT[col][k] layout (fast path) ----------
// 256 blocks x 256 threads. Block owns h-cols hc0..hc0+3 (16 gate cols).
// Thread (ks=tid>>4, j=tid&15): contiguous 64-k slice of WrT row `col`.
__global__ __launch_bounds__(256) void k_step_T(const float* __restrict__ WrT, const float* __restrict__ xw_t,
                                                float* __restrict__ seq_t, const float* __restrict__ h_in,
                                                float* __restrict__ h_out, float* __restrict__ c) {
    __shared__ float zred[4][32][17];
    int tid = threadIdx.x;
    int j = tid & 15, ks = tid >> 4;
    int hc0 = blockIdx.x * 4;
    int col = (j >> 2) * HH + hc0 + (j & 3);   // gate g = j>>2, h-col d = j&3

    // contiguous 256B slice of WrT row `col` (L2-resident across steps)
    const float4* WrT4 = (const float4*)WrT;
    int wbase = col * 256 + ks * 16;
    float4 w[16];
#pragma unroll
    for (int q = 0; q < 16; ++q) w[q] = WrT4[wbase + q];

    const float4* hp = (const float4*)h_in;
    int kq0 = ks * 16;
    float acc[32];
#pragma unroll
    for (int b = 0; b < 32; ++b) acc[b] = 0.f;
#pragma unroll
    for (int q = 0; q < 16; ++q) {
        float4 wq = w[q];
#pragma unroll
        for (int b = 0; b < 32; ++b) {
            float4 hv = hp[b * 256 + kq0 + q];
            acc[b] += wq.x * hv.x + wq.y * hv.y + wq.z * hv.z + wq.w * hv.w;
        }
    }
#pragma unroll
    for (int b = 0; b < 32; ++b) {
        acc[b] += __shfl_xor(acc[b], 16);
        acc[b] += __shfl_xor(acc[b], 32);
    }
    int wv = tid >> 6;
    if ((ks & 3) == 0) {
#pragma unroll
        for (int b = 0; b < 32; ++b) zred[wv][b][j] = acc[b];
    }
    __syncthreads();

    if (tid < 128) {
        int rb = tid >> 2, rd = tid & 3;
        float zz[4];
#pragma unroll
        for (int g = 0; g < 4; ++g) {
            float s = xw_t[rb * GG + g * HH + hc0 + rd];
#pragma unroll
            for (int u = 0; u < 4; ++u) s += zred[u][rb][g * 4 + rd];
            zz[g] = s;
        }
        float si = 1.f / (1.f + expf(-zz[0]));
        float sf = 1.f / (1.f + expf(-zz[1]));
        float gg = fmaxf(zz[2], 0.f);
        float so = 1.f / (1.f + expf(-zz[3]));
        float cv = c[rb * HH + hc0 + rd];
        cv = sf * cv + si * gg;
        c[rb * HH + hc0 + rd] = cv;
        float hn = so * fmaxf(cv, 0.f);
        h_out[rb * HH + hc0 + rd] = hn;
        seq_t[rb * HH + hc0 + rd] = hn;
    }
}

// ---------- R2 fallback step (row-major Wr), used only if ws is too small ----------
__global__ __launch_bounds__(256) void k_step(const float* __restrict__ Wr, const float* __restrict__ xw_t,
                                              float* __restrict__ seq_t, const float* __restrict__ h_in,
                                              float* __restrict__ h_out, float* __restrict__ c) {
    __shared__ float zred[4][32][17];
    int tid = threadIdx.x;
    int j = tid & 15, ks = tid >> 4;
    int hc0 = blockIdx.x * 4;
    int col = (j >> 2) * HH + hc0 + (j & 3);
    float4 w[16];
#pragma unroll
    for (int q = 0; q < 16; ++q) {
        size_t kb = (size_t)(ks * 64 + q * 4) * GG + col;
        w[q].x = Wr[kb];
        w[q].y = Wr[kb + GG];
        w[q].z = Wr[kb + 2 * (size_t)GG];
        w[q].w = Wr[kb + 3 * (size_t)GG];
    }
    const float4* hp = (const float4*)h_in;
    int kq0 = ks * 16;
    float acc[32];
#pragma unroll
    for (int b = 0; b < 32; ++b) acc[b] = 0.f;
#pragma unroll
    for (int q = 0; q < 16; ++q) {
        float4 wq = w[q];
#pragma unroll
        for (int b = 0; b < 32; ++b) {
            float4 hv = hp[b * 256 + kq0 + q];
            acc[b] += wq.x * hv.x + wq.y * hv.y + wq.z * hv.z + wq.w * hv.w;
        }
    }
#pragma unroll
    for (int b = 0; b < 32; ++b) {
        acc[b] += __shfl_xor(acc[b], 16);
        acc[b] += __shfl_xor(acc[b], 32);
    }
    int wv = tid >> 6;
    if ((ks & 3) == 0) {
#pragma unroll
        for (int b = 0; b < 32; ++b) zred[wv][b][j] = acc[b];
    }
    __syncthreads();
    if (tid < 128) {
        int rb = tid >> 2, rd = tid & 3;
        float zz[4];
#pragma unroll
        for (int g = 0; g < 4; ++g) {
            float s = xw_t[rb * GG + g * HH + hc0 + rd];
#pragma unroll
            for (int u = 0; u < 4; ++u) s += zred[u][rb][g * 4 + rd];
            zz[g] = s;
        }
        float si = 1.f / (1.f + expf(-zz[0]));
        float sf = 1.f / (1.f + expf(-zz[1]));
        float gg = fmaxf(zz[2], 0.f);
        float so = 1.f / (1.f + expf(-zz[3]));
        float cv = c[rb * HH + hc0 + rd];
        cv = sf * cv + si * gg;
        c[rb * HH + hc0 + rd] = cv;
        float hn = so * fmaxf(cv, 0.f);
        h_out[rb * HH + hc0 + rd] = hn;
        seq_t[rb * HH + hc0 + rd] = hn;
    }
}

extern "C" void kernel_launch(void* const* d_in, const int* in_sizes, int n_in,
                              void* d_out, int out_size, void* d_ws, size_t ws_size,
                              hipStream_t stream) {
    const float* x  = (const float*)d_in[0];
    const float* h0 = (const float*)d_in[1];
    const float* c0 = (const float*)d_in[2];
    const float* Wk = (const float*)d_in[3];
    const float* Wr = (const float*)d_in[4];
    const float* bs = (const float*)d_in[5];
    const float* Wd = (const float*)d_in[6];
    const float* bd = (const float*)d_in[7];
    float* out = (float*)d_out;
    float* ws  = (float*)d_ws;

    float* xw  = ws;                         // [T][B][4H]  = 33554432 f32 (128 MB)
    float* seq = ws + 33554432;              // [T][B][H]   =  8388608 f32 (32 MB)
    float* h0b = seq + 8388608;              // [B][H]
    float* h1b = h0b + 32768;                // [B][H]
    float* c   = h1b + 32768;                // [B][H]
    float* wrt = c + 32768;                  // [4096][1024] = 4194304 f32 (16 MB), reused per layer
    bool fast = ws_size >= (size_t)46235648 * 4;

    k_transpose<<<8192, 256, 0, stream>>>(x, seq);
    k_init_hc<<<32, 256, 0, stream>>>(h0, c0, h0b, c);

    for (int l = 0; l < 4; ++l) {
        const float* Wrl = Wr + (size_t)l * 1024 * 4096;
        k_gemm<0><<<dim3(64, 32), 256, 0, stream>>>(seq, Wk + (size_t)l * 1024 * 4096,
                                                    bs + l * 4096, xw, 4096);
        if (fast) k_wrt<<<dim3(64, 16), 256, 0, stream>>>(Wrl, wrt);
        for (int t = 0; t < TT; ++t) {
            const float* hin = (t & 1) ? h1b : h0b;
            float* hout      = (t & 1) ? h0b : h1b;
            if (fast)
                k_step_T<<<256, 256, 0, stream>>>(wrt, xw + (size_t)t * (BB * GG),
                                                  seq + (size_t)t * (BB * HH), hin, hout, c);
            else
                k_step<<<256, 256, 0, stream>>>(Wrl, xw + (size_t)t * (BB * GG),
                                                seq + (size_t)t * (BB * HH), hin, hout, c);
        }
    }

    k_gemm<1><<<dim3(64, 8), 256, 0, stream>>>(seq, Wd, bd, out, 1024);
    k_copy_hc<<<32, 256, 0, stream>>>(h0b, c, out + 8388608, out + 8388608 + 32768);
}

// Round 5
// 21317.776 us; speedup vs baseline: 3.0028x; 1.9429x over previous
//
#include <hip/hip_runtime.h>

#define TT 256
#define BB 32
#define HH 1024
#define GG 4096

// ---------- transpose x[B,T,H] -> seq[T,B,H] ----------
__global__ __launch_bounds__(256) void k_transpose(const float* __restrict__ x, float* __restrict__ seq) {
    int idx = blockIdx.x * 256 + threadIdx.x;  // over T*B*H/4 float4s
    int k4 = idx & 255;                        // H/4 = 256
    int tb = idx >> 8;                         // t*B + b
    int t = tb >> 5, b = tb & 31;
    float4 v = ((const float4*)x)[((size_t)b * TT + t) * 256 + k4];
    ((float4*)seq)[(size_t)tb * 256 + k4] = v;
}

__global__ __launch_bounds__(256) void k_init_hc(const float* __restrict__ h0, const float* __restrict__ c0,
                                                 float* __restrict__ h, float* __restrict__ c) {
    int i = blockIdx.x * 256 + threadIdx.x;  // 8192 float4s
    ((float4*)h)[i] = ((const float4*)h0)[i];
    ((float4*)c)[i] = ((const float4*)c0)[i];
}

__global__ __launch_bounds__(256) void k_copy_hc(const float* __restrict__ h, const float* __restrict__ c,
                                                 float* __restrict__ oh, float* __restrict__ oc) {
    int i = blockIdx.x * 256 + threadIdx.x;
    ((float4*)oh)[i] = ((const float4*)h)[i];
    ((float4*)oc)[i] = ((const float4*)c)[i];
}

// ---------- Wr[1024,4096] -> WrT[4096,1024] (64x64 LDS tiles) ----------
__global__ __launch_bounds__(256) void k_wrt(const float* __restrict__ Wr, float* __restrict__ WrT) {
    __shared__ float tile[64][65];
    int c0 = blockIdx.x * 64;   // col tile
    int k0 = blockIdx.y * 64;   // k tile
    int tid = threadIdx.x;
    int tr = tid >> 4, tc4 = tid & 15;
#pragma unroll
    for (int p = 0; p < 4; ++p) {
        int r = p * 16 + tr;
        float4 v = *(const float4*)&Wr[(size_t)(k0 + r) * GG + c0 + tc4 * 4];
        tile[r][tc4 * 4 + 0] = v.x;
        tile[r][tc4 * 4 + 1] = v.y;
        tile[r][tc4 * 4 + 2] = v.z;
        tile[r][tc4 * 4 + 3] = v.w;
    }
    __syncthreads();
#pragma unroll
    for (int p = 0; p < 4; ++p) {
        int cc = p * 16 + tr;
        float4 v;
        v.x = tile[tc4 * 4 + 0][cc];
        v.y = tile[tc4 * 4 + 1][cc];
        v.z = tile[tc4 * 4 + 2][cc];
        v.w = tile[tc4 * 4 + 3][cc];
        *(float4*)&WrT[(size_t)(c0 + cc) * 1024 + k0 + tc4 * 4] = v;
    }
}

// ---------- fp32 GEMM: C[M,N] = A[M,1024] @ W[1024,N] + bias ----------
template <int MODE>
__global__ __launch_bounds__(256) void k_gemm(const float* __restrict__ A, const float* __restrict__ W,
                                              const float* __restrict__ bias, float* __restrict__ C, int N) {
    __shared__ float As[16][132];
    __shared__ float Bs[16][132];
    const int K = 1024;
    int tid = threadIdx.x;
    int m0 = blockIdx.x * 128, n0 = blockIdx.y * 128;
    int tx = tid & 15, ty = tid >> 4;
    int a_row = tid >> 2, a_kq = tid & 3;
    int b_cq = tid & 31, b_k = tid >> 5;
    float acc[8][8];
#pragma unroll
    for (int i = 0; i < 8; ++i)
#pragma unroll
        for (int jj = 0; jj < 8; ++jj) acc[i][jj] = 0.f;

    for (int kc = 0; kc < K; kc += 16) {
#pragma unroll
        for (int it = 0; it < 2; ++it) {
            int row = a_row + it * 64;
            float4 v = *(const float4*)&A[(size_t)(m0 + row) * K + kc + a_kq * 4];
            As[a_kq * 4 + 0][row] = v.x;
            As[a_kq * 4 + 1][row] = v.y;
            As[a_kq * 4 + 2][row] = v.z;
            As[a_kq * 4 + 3][row] = v.w;
        }
#pragma unroll
        for (int it = 0; it < 2; ++it) {
            int kk = b_k + it * 8;
            float4 v = *(const float4*)&W[(size_t)(kc + kk) * N + n0 + b_cq * 4];
            *(float4*)&Bs[kk][b_cq * 4] = v;
        }
        __syncthreads();
#pragma unroll
        for (int kk = 0; kk < 16; ++kk) {
            float4 a0 = *(const float4*)&As[kk][ty * 8];
            float4 a1 = *(const float4*)&As[kk][ty * 8 + 4];
            float4 b0 = *(const float4*)&Bs[kk][tx * 8];
            float4 b1 = *(const float4*)&Bs[kk][tx * 8 + 4];
            float am[8] = {a0.x, a0.y, a0.z, a0.w, a1.x, a1.y, a1.z, a1.w};
            float bv[8] = {b0.x, b0.y, b0.z, b0.w, b1.x, b1.y, b1.z, b1.w};
#pragma unroll
            for (int i = 0; i < 8; ++i)
#pragma unroll
                for (int jj = 0; jj < 8; ++jj) acc[i][jj] += am[i] * bv[jj];
        }
        __syncthreads();
    }
#pragma unroll
    for (int i = 0; i < 8; ++i) {
        int m = m0 + ty * 8 + i;
#pragma unroll
        for (int jj = 0; jj < 8; jj += 4) {
            int n = n0 + tx * 8 + jj;
            float4 v;
            v.x = acc[i][jj + 0] + bias[n + 0];
            v.y = acc[i][jj + 1] + bias[n + 1];
            v.z = acc[i][jj + 2] + bias[n + 2];
            v.w = acc[i][jj + 3] + bias[n + 3];
            if (MODE == 0) {
                *(float4*)&C[(size_t)m * N + n] = v;
            } else {
                int t = m >> 5, b = m & 31;
                *(float4*)&C[((size_t)b * TT + t) * HH + n] = v;
            }
        }
    }
}

// ---------- one LSTM timestep, WrT layout + full-h LDS staging ----------
// 256 blocks x 256 threads, 1 block/CU. Block owns h-cols hc0..hc0+3 (16 gate cols).
// All of h (32x1024 = 128 KB) is staged into LDS once (coalesced streaming), phase A
// then reads LDS only. Skewed layout: float4-idx = b*272 + ksg*17 + q -> the 4
// ks-groups of a wave's ds_read_b128 hit disjoint bank quads; 16-lane same-address
// reads are broadcasts (free).
__global__ __launch_bounds__(256) void k_step_T2(const float* __restrict__ WrT, const float* __restrict__ xw_t,
                                                 float* __restrict__ seq_t, const float* __restrict__ h_in,
                                                 float* __restrict__ h_out, float* __restrict__ c) {
    __shared__ float h_lds[34816];        // 32 * 1088 floats = 139 KB
    __shared__ float zred[4][32][17];
    int tid = threadIdx.x;
    int j = tid & 15, ks = tid >> 4;
    int hc0 = blockIdx.x * 4;
    int col = (j >> 2) * HH + hc0 + (j & 3);   // gate g = j>>2, h-col d = j&3

    // issue WrT register loads first (contiguous 256B slice, L2/L3-warm)
    const float4* WrT4 = (const float4*)WrT;
    int wbase = col * 256 + ks * 16;
    float4 w[16];
#pragma unroll
    for (int q = 0; q < 16; ++q) w[q] = WrT4[wbase + q];

    // issue xw loads early (consumed in the epilogue)
    int rb = tid >> 2, rd = tid & 3;
    float pz[4];
    if (tid < 128) {
#pragma unroll
        for (int g = 0; g < 4; ++g) pz[g] = xw_t[rb * GG + g * HH + hc0 + rd];
    }

    // stage all of h into LDS, coalesced
    const float4* hp4 = (const float4*)h_in;
    float4* hl4w = (float4*)h_lds;
#pragma unroll 8
    for (int it = 0; it < 32; ++it) {
        int gi = it * 256 + tid;           // float4 index into h_in (8192 total)
        float4 v = hp4[gi];
        int b = gi >> 8, kk = gi & 255;    // kk: float4-k within the batch row
        hl4w[b * 272 + (kk >> 4) * 17 + (kk & 15)] = v;
    }
    __syncthreads();

    // phase A: partial z = h @ Wr over this thread's 64-k slice, all 32 batches
    const float4* hl4 = (const float4*)h_lds;
    int base4 = ks * 17;
    float acc[32];
#pragma unroll
    for (int b = 0; b < 32; ++b) acc[b] = 0.f;
#pragma unroll
    for (int q = 0; q < 16; ++q) {
        float4 wq = w[q];
#pragma unroll
        for (int b = 0; b < 32; ++b) {
            float4 hv = hl4[b * 272 + base4 + q];
            acc[b] += wq.x * hv.x + wq.y * hv.y + wq.z * hv.z + wq.w * hv.w;
        }
    }
    // reduce the 4 k-slices within each wave (lane = (ks&3)*16 + j)
#pragma unroll
    for (int b = 0; b < 32; ++b) {
        acc[b] += __shfl_xor(acc[b], 16);
        acc[b] += __shfl_xor(acc[b], 32);
    }
    int wv = tid >> 6;
    if ((ks & 3) == 0) {
#pragma unroll
        for (int b = 0; b < 32; ++b) zred[wv][b][j] = acc[b];
    }
    __syncthreads();

    // reduce across waves + gates + state update
    if (tid < 128) {
        float zz[4];
#pragma unroll
        for (int g = 0; g < 4; ++g) {
            float s = pz[g];
#pragma unroll
            for (int u = 0; u < 4; ++u) s += zred[u][rb][g * 4 + rd];
            zz[g] = s;
        }
        float si = 1.f / (1.f + expf(-zz[0]));
        float sf = 1.f / (1.f + expf(-zz[1]));
        float gg = fmaxf(zz[2], 0.f);
        float so = 1.f / (1.f + expf(-zz[3]));
        float cv = c[rb * HH + hc0 + rd];
        cv = sf * cv + si * gg;
        c[rb * HH + hc0 + rd] = cv;
        float hn = so * fmaxf(cv, 0.f);
        h_out[rb * HH + hc0 + rd] = hn;
        seq_t[rb * HH + hc0 + rd] = hn;
    }
}

// ---------- fallback step (row-major Wr), used only if ws is too small ----------
__global__ __launch_bounds__(256) void k_step(const float* __restrict__ Wr, const float* __restrict__ xw_t,
                                              float* __restrict__ seq_t, const float* __restrict__ h_in,
                                              float* __restrict__ h_out, float* __restrict__ c) {
    __shared__ float zred[4][32][17];
    int tid = threadIdx.x;
    int j = tid & 15, ks = tid >> 4;
    int hc0 = blockIdx.x * 4;
    int col = (j >> 2) * HH + hc0 + (j & 3);
    float4 w[16];
#pragma unroll
    for (int q = 0; q < 16; ++q) {
        size_t kb = (size_t)(ks * 64 + q * 4) * GG + col;
        w[q].x = Wr[kb];
        w[q].y = Wr[kb + GG];
        w[q].z = Wr[kb + 2 * (size_t)GG];
        w[q].w = Wr[kb + 3 * (size_t)GG];
    }
    const float4* hp = (const float4*)h_in;
    int kq0 = ks * 16;
    float acc[32];
#pragma unroll
    for (int b = 0; b < 32; ++b) acc[b] = 0.f;
#pragma unroll
    for (int q = 0; q < 16; ++q) {
        float4 wq = w[q];
#pragma unroll
        for (int b = 0; b < 32; ++b) {
            float4 hv = hp[b * 256 + kq0 + q];
            acc[b] += wq.x * hv.x + wq.y * hv.y + wq.z * hv.z + wq.w * hv.w;
        }
    }
#pragma unroll
    for (int b = 0; b < 32; ++b) {
        acc[b] += __shfl_xor(acc[b], 16);
        acc[b] += __shfl_xor(acc[b], 32);
    }
    int wv = tid >> 6;
    if ((ks & 3) == 0) {
#pragma unroll
        for (int b = 0; b < 32; ++b) zred[wv][b][j] = acc[b];
    }
    __syncthreads();
    if (tid < 128) {
        int rb = tid >> 2, rd = tid & 3;
        float zz[4];
#pragma unroll
        for (int g = 0; g < 4; ++g) {
            float s = xw_t[rb * GG + g * HH + hc0 + rd];
#pragma unroll
            for (int u = 0; u < 4; ++u) s += zred[u][rb][g * 4 + rd];
            zz[g] = s;
        }
        float si = 1.f / (1.f + expf(-zz[0]));
        float sf = 1.f / (1.f + expf(-zz[1]));
        float gg = fmaxf(zz[2], 0.f);
        float so = 1.f / (1.f + expf(-zz[3]));
        float cv = c[rb * HH + hc0 + rd];
        cv = sf * cv + si * gg;
        c[rb * HH + hc0 + rd] = cv;
        float hn = so * fmaxf(cv, 0.f);
        h_out[rb * HH + hc0 + rd] = hn;
        seq_t[rb * HH + hc0 + rd] = hn;
    }
}

extern "C" void kernel_launch(void* const* d_in, const int* in_sizes, int n_in,
                              void* d_out, int out_size, void* d_ws, size_t ws_size,
                              hipStream_t stream) {
    const float* x  = (const float*)d_in[0];
    const float* h0 = (const float*)d_in[1];
    const float* c0 = (const float*)d_in[2];
    const float* Wk = (const float*)d_in[3];
    const float* Wr = (const float*)d_in[4];
    const float* bs = (const float*)d_in[5];
    const float* Wd = (const float*)d_in[6];
    const float* bd = (const float*)d_in[7];
    float* out = (float*)d_out;
    float* ws  = (float*)d_ws;

    float* xw  = ws;                         // [T][B][4H]  = 33554432 f32 (128 MB)
    float* seq = ws + 33554432;              // [T][B][H]   =  8388608 f32 (32 MB)
    float* h0b = seq + 8388608;              // [B][H]
    float* h1b = h0b + 32768;                // [B][H]
    float* c   = h1b + 32768;                // [B][H]
    float* wrt = c + 32768;                  // [4096][1024] = 4194304 f32 (16 MB), reused per layer
    bool fast = ws_size >= (size_t)46235648 * 4;

    k_transpose<<<8192, 256, 0, stream>>>(x, seq);
    k_init_hc<<<32, 256, 0, stream>>>(h0, c0, h0b, c);

    for (int l = 0; l < 4; ++l) {
        const float* Wrl = Wr + (size_t)l * 1024 * 4096;
        k_gemm<0><<<dim3(64, 32), 256, 0, stream>>>(seq, Wk + (size_t)l * 1024 * 4096,
                                                    bs + l * 4096, xw, 4096);
        if (fast) k_wrt<<<dim3(64, 16), 256, 0, stream>>>(Wrl, wrt);
        for (int t = 0; t < TT; ++t) {
            const float* hin = (t & 1) ? h1b : h0b;
            float* hout      = (t & 1) ? h0b : h1b;
            if (fast)
                k_step_T2<<<256, 256, 0, stream>>>(wrt, xw + (size_t)t * (BB * GG),
                                                   seq + (size_t)t * (BB * HH), hin, hout, c);
            else
                k_step<<<256, 256, 0, stream>>>(Wrl, xw + (size_t)t * (BB * GG),
                                                seq + (size_t)t * (BB * HH), hin, hout, c);
        }
    }

    k_gemm<1><<<dim3(64, 8), 256, 0, stream>>>(seq, Wd, bd, out, 1024);
    k_copy_hc<<<32, 256, 0, stream>>>(h0b, c, out + 8388608, out + 8388608 + 32768);
}